// Round 12
// baseline (374.805 us; speedup 1.0000x reference)
//
#include <hip/hip_runtime.h>
#include <hip/hip_bf16.h>
#include <cfloat>

typedef __attribute__((ext_vector_type(8))) short bf16x8;
typedef __attribute__((ext_vector_type(4))) float f32x4;

#define M_DIM 8192
#define N_DIM 4096
#define K_DIM 4096

__device__ inline ushort f2bf(float f) {
    unsigned u = __float_as_uint(f);
    unsigned r = (u + 0x7FFFu + ((u >> 16) & 1u)) >> 16;
    return (ushort)r;
}

// swizzle: XOR 16B-slot index (bits 4-6) with row low bits (bits 7-9). Involution.
#define SWZ(x) ((x) ^ ((((x) >> 7) & 7) << 4))

// ---------------- kernel 1: weight 4-bit group-128 qdq -> bf16, PACKED frag layout ----
// wq layout: [nb(16)][wn4(4)][T(64)][kk(2)][ni4(4)][lane(64)][8 elems]
__global__ __launch_bounds__(256) void w_dq_pack(const float* __restrict__ w,
                                                 ushort* __restrict__ wq) {
    int bx = blockIdx.x;                 // 64 row-blocks * 32 k-groups = 2048
    int n0 = (bx >> 5) * 64;
    int kg = bx & 31;
    int t = threadIdx.x;
    int n = n0 + (t >> 2);
    int kq = t & 3;
    const float* src = w + (size_t)n * K_DIM + kg * 128 + kq * 32;
    float4 v[8];
    float mn = FLT_MAX, mx = -FLT_MAX;
#pragma unroll
    for (int j = 0; j < 8; j++) {
        v[j] = ((const float4*)src)[j];
        mn = fminf(mn, fminf(fminf(v[j].x, v[j].y), fminf(v[j].z, v[j].w)));
        mx = fmaxf(mx, fmaxf(fmaxf(v[j].x, v[j].y), fmaxf(v[j].z, v[j].w)));
    }
    mn = fminf(mn, __shfl_xor(mn, 1)); mx = fmaxf(mx, __shfl_xor(mx, 1));
    mn = fminf(mn, __shfl_xor(mn, 2)); mx = fmaxf(mx, __shfl_xor(mx, 2));
    float scale = (mx - mn) / 15.0f;
    float zero  = -8.0f - rintf(mn / scale);

    int nb = n >> 8, wn = (n >> 6) & 3, ni = (n >> 4) & 3, lr = n & 15;
    int T = kg * 2 + (kq >> 1), kk = kq & 1;
    size_t base16 = ((((size_t)(nb * 4 + wn) * 64 + T) * 2 + kk) * 4 + ni) * 64;
#pragma unroll
    for (int lh = 0; lh < 4; lh++) {
        bf16x8 o;
#pragma unroll
        for (int e = 0; e < 8; e++) {
            float4 vv = v[lh * 2 + (e >> 2)];
            float x = (e & 3) == 0 ? vv.x : (e & 3) == 1 ? vv.y : (e & 3) == 2 ? vv.z : vv.w;
            float q = fminf(fmaxf(rintf(x / scale) + zero, -8.0f), 7.0f);
            o[e] = (short)f2bf((q - zero) * scale);
        }
        *(bf16x8*)(wq + (base16 + lh * 16 + lr) * 8) = o;
    }
}

// ---------------- kernel 2: per-row int8 act quant-dequant -> bf16 (row-major) --------
__global__ __launch_bounds__(256) void act_qdq(const float* __restrict__ x,
                                               ushort* __restrict__ xq) {
    __shared__ float smn[4], smx[4];
    int row = blockIdx.x;
    const float* xr = x + (size_t)row * K_DIM;
    ushort* xo = xq + (size_t)row * K_DIM;
    int t = threadIdx.x;
    float4 v[4];
    float mn = FLT_MAX, mx = -FLT_MAX;
#pragma unroll
    for (int i = 0; i < 4; i++) {
        v[i] = ((const float4*)xr)[t + i * 256];
        mn = fminf(mn, fminf(fminf(v[i].x, v[i].y), fminf(v[i].z, v[i].w)));
        mx = fmaxf(mx, fmaxf(fmaxf(v[i].x, v[i].y), fmaxf(v[i].z, v[i].w)));
    }
#pragma unroll
    for (int s = 1; s < 64; s <<= 1) {
        mn = fminf(mn, __shfl_xor(mn, s));
        mx = fmaxf(mx, __shfl_xor(mx, s));
    }
    int w = t >> 6;
    if ((t & 63) == 0) { smn[w] = mn; smx[w] = mx; }
    __syncthreads();
    mn = fminf(fminf(smn[0], smn[1]), fminf(smn[2], smn[3]));
    mx = fmaxf(fmaxf(smx[0], smx[1]), fmaxf(smx[2], smx[3]));
    float scale = (mx - mn) / 255.0f;
    float zero  = -128.0f - rintf(mn / scale);
#pragma unroll
    for (int i = 0; i < 4; i++) {
        ushort4 o;
        float q;
        q = fminf(fmaxf(rintf(v[i].x / scale) + zero, -128.0f), 127.0f); o.x = f2bf((q - zero) * scale);
        q = fminf(fmaxf(rintf(v[i].y / scale) + zero, -128.0f), 127.0f); o.y = f2bf((q - zero) * scale);
        q = fminf(fmaxf(rintf(v[i].z / scale) + zero, -128.0f), 127.0f); o.z = f2bf((q - zero) * scale);
        q = fminf(fmaxf(rintf(v[i].w / scale) + zero, -128.0f), 127.0f); o.w = f2bf((q - zero) * scale);
        ((ushort4*)xo)[t + i * 256] = o;
    }
}

// ---------------- kernel 3: 256x256 bf16 GEMM; 4x2 wave grid, A via LDS, B direct ----
// A-redundancy fix: wm = w>>1 (4 m-strips), wn = w&1 -> A frag LDS traffic 96KB/K-tile
// (was 256KB+) << MFMA 2520cyc. B redundancy lands on the L2 pipe (packed layout,
// stripe swizzle keeps per-XCD B slice 2MB <= 4MB L2). One barrier per K-tile.
#define BM 256
#define BN 256
#define BK 64
#define NT (K_DIM / BK)   /* 64 K-tiles */

__global__ __launch_bounds__(512, 1) void gemm_bt8(const ushort* __restrict__ A,
                                                   const ushort* __restrict__ Bp,
                                                   float* __restrict__ C) {
    __shared__ __align__(16) ushort As[2][BM * BK];   // 2 x 32 KiB, quarter rq at byte rq*8192

    // stripe swizzle: xcd = orig&7 owns nb in {2*xcd, 2*xcd+1}; concurrent j<32 share nb.
    int orig = blockIdx.x;
    int xcd = orig & 7, j = orig >> 3;          // j in 0..63
    int nb = xcd * 2 + (j >> 5);                // 0..15
    int mb = j & 31;                            // 0..31
    size_t m0 = (size_t)mb * BM;

    const int t = threadIdx.x;
    const int w = t >> 6, lane = t & 63;
    const int wm = w >> 1, wn = w & 1;          // 4 x 2 wave grid; per-wave out 64x128
    const int lr = lane & 15;
    const int lk = (lane >> 4) << 3;

    const ushort* Ab = A + m0 * K_DIM;
    const int nbase = nb * 4 + wn * 2;          // wn4 group base for this wave

    f32x4 acc[4][8] = {};
    bf16x8 afr[2];         // per-mi-phase, reused
    bf16x8 bfr[8][2];      // whole tile's B frags (64 VGPR)

#define STAGEALL(dd, T) do {                                                      \
    _Pragma("unroll") for (int rq = 0; rq < 4; rq++) {                            \
        int base = rq * 8192 + w * 1024;                                          \
        int lb = base + lane * 16;                                                \
        int lg = SWZ(lb);                                                         \
        __builtin_amdgcn_global_load_lds(                                         \
            (const __attribute__((address_space(1))) unsigned int*)(Ab + (size_t)(lg >> 7) * K_DIM + (T) * BK + ((lg & 127) >> 1)), \
            (__attribute__((address_space(3))) unsigned int*)((char*)As[dd] + base), \
            16, 0, 0);                                                            \
    } } while (0)

#define LOADB_ALL(T) do {                                                         \
    _Pragma("unroll") for (int ni = 0; ni < 8; ni++)                              \
    _Pragma("unroll") for (int kk = 0; kk < 2; kk++)                              \
        bfr[ni][kk] = *(const bf16x8*)(Bp +                                       \
            ((((size_t)(nbase + (ni >> 2)) * 64 + (T)) * 2 + kk) * 4 + (ni & 3)) * 512 + lane * 8); \
    } while (0)

#define LOADA_PH(mi, dd) do {                                                     \
    _Pragma("unroll") for (int kk = 0; kk < 2; kk++) {                            \
        int row = wm * 64 + (mi) * 16 + lr;                                       \
        int lg = row * 128 + (kk * 32 + lk) * 2;                                  \
        afr[kk] = *(const bf16x8*)((const char*)As[dd] + SWZ(lg));                \
    } } while (0)

#define MFMA_PH(mi) do {                                                          \
    __builtin_amdgcn_s_setprio(1);                                                \
    _Pragma("unroll") for (int kk = 0; kk < 2; kk++)                              \
    _Pragma("unroll") for (int ni = 0; ni < 8; ni++)                              \
        acc[mi][ni] = __builtin_amdgcn_mfma_f32_16x16x32_bf16(                    \
            afr[kk], bfr[ni][kk], acc[mi][ni], 0, 0, 0);                          \
    __builtin_amdgcn_s_setprio(0);                                                \
  } while (0)

#define PH(mi, dd) do {                                                           \
    LOADA_PH(mi, dd);                                                             \
    asm volatile("s_waitcnt lgkmcnt(0)" ::: "memory");                            \
    __builtin_amdgcn_sched_barrier(0);                                            \
    MFMA_PH(mi);                                                                  \
  } while (0)

#define ITER(d, T) do {                                                           \
    LOADB_ALL(T);                   /* 16 vmem, oldest in queue */                \
    if ((T) + 1 < NT) STAGEALL((d) ^ 1, (T) + 1);                                 \
    PH(0, d);                       /* compiler drains B (vmcnt(4)) here */       \
    PH(1, d);                                                                     \
    PH(2, d);                                                                     \
    PH(3, d);                                                                     \
    asm volatile("s_waitcnt vmcnt(0)" ::: "memory");   /* stages ~2400cy old */   \
    __builtin_amdgcn_s_barrier();                                                 \
    __builtin_amdgcn_sched_barrier(0);                                            \
  } while (0)

    // prologue: stage A(0), drain, sync
    STAGEALL(0, 0);
    asm volatile("s_waitcnt vmcnt(0)" ::: "memory");
    __builtin_amdgcn_s_barrier();
    __builtin_amdgcn_sched_barrier(0);

#pragma unroll 1
    for (int i = 0; i < NT / 2; i++) {
        ITER(0, 2 * i);
        ITER(1, 2 * i + 1);
    }
#undef ITER
#undef PH
#undef MFMA_PH
#undef LOADA_PH
#undef LOADB_ALL
#undef STAGEALL

    // C write: acc[mi][ni] -> row = m0 + wm*64 + mi*16 + fq*4 + r ; col = n0 + wn*128 + ni*16 + lr
    size_t n0 = (size_t)nb * BN;
    int fq = lane >> 4;
#pragma unroll
    for (int mi = 0; mi < 4; mi++) {
#pragma unroll
        for (int ni = 0; ni < 8; ni++) {
#pragma unroll
            for (int r = 0; r < 4; r++) {
                size_t crow = m0 + wm * 64 + mi * 16 + fq * 4 + r;
                C[crow * N_DIM + n0 + wn * 128 + ni * 16 + lr] = acc[mi][ni][r];
            }
        }
    }
}

extern "C" void kernel_launch(void* const* d_in, const int* in_sizes, int n_in,
                              void* d_out, int out_size, void* d_ws, size_t ws_size,
                              hipStream_t stream) {
    const float* x = (const float*)d_in[0];
    const float* w = (const float*)d_in[1];
    float* out = (float*)d_out;

    ushort* wq = (ushort*)d_ws;                                        // 32 MiB (packed)
    ushort* xq = (ushort*)((char*)d_ws + (size_t)N_DIM * K_DIM * 2);   // 64 MiB

    hipLaunchKernelGGL(w_dq_pack, dim3((N_DIM / 64) * (K_DIM / 128)), dim3(256), 0, stream, w, wq);
    hipLaunchKernelGGL(act_qdq, dim3(M_DIM), dim3(256), 0, stream, x, xq);
    hipLaunchKernelGGL(gemm_bt8, dim3((M_DIM / BM) * (N_DIM / BN)), dim3(512), 0, stream, xq, wq, out);
}

// Round 13
// 304.474 us; speedup vs baseline: 1.2310x; 1.2310x over previous
//
#include <hip/hip_runtime.h>
#include <hip/hip_bf16.h>
#include <cfloat>

typedef __attribute__((ext_vector_type(8))) short bf16x8;
typedef __attribute__((ext_vector_type(4))) float f32x4;

#define M_DIM 8192
#define N_DIM 4096
#define K_DIM 4096

__device__ inline ushort f2bf(float f) {
    unsigned u = __float_as_uint(f);
    unsigned r = (u + 0x7FFFu + ((u >> 16) & 1u)) >> 16;
    return (ushort)r;
}

// swizzle: XOR 16B-slot index (bits 4-6) with row low bits (bits 7-9). Involution.
#define SWZ(x) ((x) ^ ((((x) >> 7) & 7) << 4))

// ---------------- kernel 1: weight 4-bit group-128 quant-dequant -> bf16 (row-major) --
__global__ __launch_bounds__(256) void w_dequant(const float* __restrict__ w,
                                                 ushort* __restrict__ wq) {
    int g = blockIdx.x * 4 + (threadIdx.x >> 6);
    int lane = threadIdx.x & 63;
    const float* src = w + (size_t)g * 128;
    float2 v = *(const float2*)(src + lane * 2);
    float mn = fminf(v.x, v.y), mx = fmaxf(v.x, v.y);
#pragma unroll
    for (int s = 1; s < 64; s <<= 1) {
        mn = fminf(mn, __shfl_xor(mn, s));
        mx = fmaxf(mx, __shfl_xor(mx, s));
    }
    float scale = (mx - mn) / 15.0f;
    float zero  = -8.0f - rintf(mn / scale);
    float q0 = fminf(fmaxf(rintf(v.x / scale) + zero, -8.0f), 7.0f);
    float q1 = fminf(fmaxf(rintf(v.y / scale) + zero, -8.0f), 7.0f);
    ushort2 o;
    o.x = f2bf((q0 - zero) * scale);
    o.y = f2bf((q1 - zero) * scale);
    *(ushort2*)(wq + (size_t)g * 128 + lane * 2) = o;
}

// ---------------- kernel 2: per-row int8 act quant-dequant -> bf16 ----------------
__global__ __launch_bounds__(256) void act_qdq(const float* __restrict__ x,
                                               ushort* __restrict__ xq) {
    __shared__ float smn[4], smx[4];
    int row = blockIdx.x;
    const float* xr = x + (size_t)row * K_DIM;
    ushort* xo = xq + (size_t)row * K_DIM;
    int t = threadIdx.x;
    float4 v[4];
    float mn = FLT_MAX, mx = -FLT_MAX;
#pragma unroll
    for (int i = 0; i < 4; i++) {
        v[i] = ((const float4*)xr)[t + i * 256];
        mn = fminf(mn, fminf(fminf(v[i].x, v[i].y), fminf(v[i].z, v[i].w)));
        mx = fmaxf(mx, fmaxf(fmaxf(v[i].x, v[i].y), fmaxf(v[i].z, v[i].w)));
    }
#pragma unroll
    for (int s = 1; s < 64; s <<= 1) {
        mn = fminf(mn, __shfl_xor(mn, s));
        mx = fmaxf(mx, __shfl_xor(mx, s));
    }
    int w = t >> 6;
    if ((t & 63) == 0) { smn[w] = mn; smx[w] = mx; }
    __syncthreads();
    mn = fminf(fminf(smn[0], smn[1]), fminf(smn[2], smn[3]));
    mx = fmaxf(fmaxf(smx[0], smx[1]), fmaxf(smx[2], smx[3]));
    float scale = (mx - mn) / 255.0f;
    float zero  = -128.0f - rintf(mn / scale);
#pragma unroll
    for (int i = 0; i < 4; i++) {
        ushort4 o;
        float q;
        q = fminf(fmaxf(rintf(v[i].x / scale) + zero, -128.0f), 127.0f); o.x = f2bf((q - zero) * scale);
        q = fminf(fmaxf(rintf(v[i].y / scale) + zero, -128.0f), 127.0f); o.y = f2bf((q - zero) * scale);
        q = fminf(fmaxf(rintf(v[i].z / scale) + zero, -128.0f), 127.0f); o.z = f2bf((q - zero) * scale);
        q = fminf(fmaxf(rintf(v[i].w / scale) + zero, -128.0f), 127.0f); o.w = f2bf((q - zero) * scale);
        ((ushort4*)xo)[t + i * 256] = o;
    }
}

// ---------------- kernel 3: 256x256 8-phase bf16 GEMM (r5 schedule + hoisted addrs) ---
// All ds_read addresses are ONE precomputed VGPR base per (array, kk) + 16-bit imm
// offset (exact because row%8 == lr%8 for every fragment row). Stage sources hoisted
// to off_q[rq]. Zero per-phase address VALU. Schedule identical to round-5 (passed).
#define BM 256
#define BN 256
#define BK 64
#define NT (K_DIM / BK)   /* 64 K-tiles */

__global__ __launch_bounds__(512, 1) void gemm_bt8(const ushort* __restrict__ A,
                                                   const ushort* __restrict__ B,
                                                   float* __restrict__ C) {
    __shared__ __align__(16) ushort As[2][BM * BK];   // quarter rq at byte rq*8192
    __shared__ __align__(16) ushort Bs[2][BN * BK];

    const int nbx = N_DIM / BN;                 // 16
    const int nwg = (M_DIM / BM) * nbx;         // 512 (%8==0)
    int bid = blockIdx.x;
    bid = (bid & 7) * (nwg / 8) + (bid >> 3);   // bijective XCD swizzle
    int mb = bid / nbx, nb = bid % nbx;
    size_t m0 = (size_t)mb * BM, n0 = (size_t)nb * BN;

    const int t = threadIdx.x;
    const int w = t >> 6, lane = t & 63;
    const int wm = w >> 2, wn = w & 3;          // 2 x 4 wave grid
    const int lr = lane & 15;
    const int lk = (lane >> 4) << 3;

    const ushort* Ab = A + m0 * K_DIM;
    const ushort* Bb = B + n0 * K_DIM;

    // hoisted swizzled lane-parts: phys = row*128 + (colbyte ^ ((lr&7)<<4)), row%8==lr%8
    const int mask7 = (lr & 7) << 4;
    const int lp0 = lr * 128 + ((lk * 2) ^ mask7);          // kk=0
    const int lp1 = lr * 128 + ((64 + lk * 2) ^ mask7);     // kk=1
    const char* A_k0 = (const char*)As + wm * 4096 + lp0;   // + wm*32 rows baked in
    const char* A_k1 = (const char*)As + wm * 4096 + lp1;
    const char* B_k0 = (const char*)Bs + wn * 8192 + lp0;   // + wn*64 rows baked in
    const char* B_k1 = (const char*)Bs + wn * 8192 + lp1;

    // hoisted stage source offsets (elements) and dest bytes per row-quarter
    int off_q[4], dst_q[4];
#pragma unroll
    for (int rq = 0; rq < 4; rq++) {
        int base = rq * 8192 + w * 1024;
        int lg = SWZ(base + lane * 16);
        off_q[rq] = (lg >> 7) * K_DIM + ((lg & 127) >> 1);
        dst_q[rq] = base;
    }

    // stage one 8KB quarter: qq 0-3 = A rows qq*64.., qq 4-7 = B rows (qq-4)*64..
    auto STAGE = [&](int T, int qq) {
        if (T >= NT) return;
        int d = T & 1;
        bool isA = qq < 4;
        int rq = qq & 3;
        ushort* l = isA ? As[d] : Bs[d];
        const ushort* g = (isA ? Ab : Bb) + (size_t)T * BK + off_q[rq];
        __builtin_amdgcn_global_load_lds(
            (const __attribute__((address_space(1))) unsigned int*)g,
            (__attribute__((address_space(3))) unsigned int*)((char*)l + dst_q[rq]),
            16, 0, 0);
    };

    f32x4 acc[8][4] = {};
    bf16x8 afr[2][2];   // [ii][kk] read each phase
    bf16x8 bfr[4][2];   // [ni][kk] read at q0, live 4 phases

    // A read: quarter q, half ii, buffer d  ->  base_kk + imm
#define LOADA(d, q) do {                                                          \
    _Pragma("unroll") for (int ii = 0; ii < 2; ii++) {                            \
        afr[ii][0] = *(const bf16x8*)(A_k0 + (d) * 32768 + ((q) * 64 + ii * 16) * 128); \
        afr[ii][1] = *(const bf16x8*)(A_k1 + (d) * 32768 + ((q) * 64 + ii * 16) * 128); \
    } } while (0)
#define LOADB(d) do {                                                             \
    _Pragma("unroll") for (int ni = 0; ni < 4; ni++) {                            \
        bfr[ni][0] = *(const bf16x8*)(B_k0 + (d) * 32768 + ni * 2048);            \
        bfr[ni][1] = *(const bf16x8*)(B_k1 + (d) * 32768 + ni * 2048);            \
    } } while (0)

#define PHASE(d, q, sT1, sq1, sT2, sq2, vm) do {                                  \
    if ((q) == 0) LOADB(d);                                                       \
    LOADA(d, q);                                                                  \
    STAGE(sT1, sq1);                                                              \
    STAGE(sT2, sq2);                                                              \
    __builtin_amdgcn_s_barrier();                                                 \
    asm volatile("s_waitcnt lgkmcnt(0)" ::: "memory");                            \
    __builtin_amdgcn_sched_barrier(0);                                            \
    __builtin_amdgcn_s_setprio(1);                                                \
    _Pragma("unroll") for (int kk = 0; kk < 2; kk++)                              \
    _Pragma("unroll") for (int ii = 0; ii < 2; ii++)                              \
    _Pragma("unroll") for (int ni = 0; ni < 4; ni++)                              \
        acc[(q) * 2 + ii][ni] = __builtin_amdgcn_mfma_f32_16x16x32_bf16(          \
            afr[ii][kk], bfr[ni][kk], acc[(q) * 2 + ii][ni], 0, 0, 0);            \
    __builtin_amdgcn_s_setprio(0);                                                \
    if ((vm) == 1) asm volatile("s_waitcnt vmcnt(8)" ::: "memory");               \
    if ((vm) == 2) asm volatile("s_waitcnt vmcnt(0)" ::: "memory");               \
    __builtin_amdgcn_s_barrier();                                                 \
  } while (0)

    // prologue: tile0 all 8 quarters, tile1 B quarters, tile1 A0,A1; tile0 landed
    STAGE(0, 0); STAGE(0, 1); STAGE(0, 2); STAGE(0, 3);
    STAGE(0, 4); STAGE(0, 5); STAGE(0, 6); STAGE(0, 7);
    STAGE(1, 4); STAGE(1, 5); STAGE(1, 6); STAGE(1, 7);
    STAGE(1, 0); STAGE(1, 1);
    asm volatile("s_waitcnt vmcnt(6)" ::: "memory");
    __builtin_amdgcn_s_barrier();

    // main: iters 0..NT/2-2 (r5 slot table, leads >=4 phases, overwrite-after-death)
#pragma unroll 1
    for (int i = 0; i < NT / 2 - 1; i++) {
        int T0 = 2 * i;
        PHASE(0, 0, T0 + 1, 2, T0 + 1, 3, 1);
        PHASE(0, 1, T0 + 2, 4, T0 + 2, 5, 1);
        PHASE(0, 2, T0 + 2, 6, T0 + 2, 7, 1);
        PHASE(0, 3, T0 + 2, 0, T0 + 2, 1, 1);
        PHASE(1, 0, T0 + 2, 2, T0 + 2, 3, 1);
        PHASE(1, 1, T0 + 3, 4, T0 + 3, 5, 1);
        PHASE(1, 2, T0 + 3, 6, T0 + 3, 7, 1);
        PHASE(1, 3, T0 + 3, 0, T0 + 3, 1, 1);
    }

    // peeled last iter (tiles NT-2, NT-1): stage NT-1's A[2],A[3]; drain at ph3
    PHASE(0, 0, NT - 1, 2, NT - 1, 3, 1);
    PHASE(0, 1, NT, 0, NT, 0, 1);
    PHASE(0, 2, NT, 0, NT, 0, 1);
    PHASE(0, 3, NT, 0, NT, 0, 2);   // vmcnt(0): tile NT-1 landed
    PHASE(1, 0, NT, 0, NT, 0, 0);
    PHASE(1, 1, NT, 0, NT, 0, 0);
    PHASE(1, 2, NT, 0, NT, 0, 0);
    PHASE(1, 3, NT, 0, NT, 0, 0);
#undef PHASE
#undef LOADA
#undef LOADB

    // C write: acc[mi][ni], mi = q*2+ii -> row = m0 + (mi>>1)*64 + wm*32 + (mi&1)*16 + fq*4 + r
    int fq = lane >> 4;
#pragma unroll
    for (int mi = 0; mi < 8; mi++) {
#pragma unroll
        for (int ni = 0; ni < 4; ni++) {
#pragma unroll
            for (int r = 0; r < 4; r++) {
                size_t crow = m0 + (mi >> 1) * 64 + wm * 32 + (mi & 1) * 16 + fq * 4 + r;
                C[crow * N_DIM + n0 + wn * 64 + ni * 16 + lr] = acc[mi][ni][r];
            }
        }
    }
}

extern "C" void kernel_launch(void* const* d_in, const int* in_sizes, int n_in,
                              void* d_out, int out_size, void* d_ws, size_t ws_size,
                              hipStream_t stream) {
    const float* x = (const float*)d_in[0];
    const float* w = (const float*)d_in[1];
    float* out = (float*)d_out;

    ushort* wq = (ushort*)d_ws;                                        // 32 MiB
    ushort* xq = (ushort*)((char*)d_ws + (size_t)N_DIM * K_DIM * 2);   // 64 MiB

    hipLaunchKernelGGL(w_dequant, dim3((N_DIM * K_DIM / 128) / 4), dim3(256), 0, stream, w, wq);
    hipLaunchKernelGGL(act_qdq, dim3(M_DIM), dim3(256), 0, stream, x, xq);
    hipLaunchKernelGGL(gemm_bt8, dim3((M_DIM / BM) * (N_DIM / BN)), dim3(512), 0, stream, xq, wq, out);
}